// Round 3
// baseline (91.169 us; speedup 1.0000x reference)
//
#include <hip/hip_runtime.h>

// Problem constants (x: [128, 65536] fp32, LEVEL=8)
static constexpr int BROWS = 128;   // batch rows
static constexpr int T     = 65536; // samples per row
static constexpr int CL    = 256;   // chunk length = 2^LEVEL
static constexpr int NCH   = 256;   // chunks per row = T / CL (positions per node)
static constexpr int NODES = 256;   // 2^LEVEL leaves
static constexpr int KG    = 32;    // chunks per phase
static constexpr int NPH   = NCH / KG; // 8 phases per row
static constexpr int LSTR  = 257;   // padded LDS row stride (breaks bank conflicts)
static constexpr int NTHR  = 512;   // 8 waves per block, 1 block per row

// Output row for Hadamard-order index h (in-place FWHT leaves Hadamard order):
//   c_nat[n] = H[bitrev8(n)], freq perm out[m] = c_nat[gray^-1(m)] => m = gray(bitrev8(h))
__device__ __forceinline__ int freq_pos(int h) {
    unsigned r = __brev((unsigned)h) >> 24; // bitrev8
    return (int)(r ^ (r >> 1));             // gray code
}

__device__ __forceinline__ void bfly01(float4& v) {
    // FWHT stages on j-bits 0,1 (within the float4)
    float4 w;
    w.x = v.x + v.y; w.y = v.x - v.y;
    w.z = v.z + v.w; w.w = v.z - v.w;
    v.x = w.x + w.z; v.z = w.x - w.z;
    v.y = w.y + w.w; v.w = w.y - w.w;
}

// Lane-exchange via DPP (VALU pipe — no LDS traffic). HW-validated.
// xor1 = quad_perm [1,0,3,2] = 0xB1; xor2 = quad_perm [2,3,0,1] = 0x4E;
// xor8 = row_ror:8 = 0x128 ((i+8)%16 == i^8 within a 16-lane row).
template<int CTRL>
__device__ __forceinline__ float xchg_dpp(float v) {
    return __builtin_bit_cast(float,
        __builtin_amdgcn_update_dpp(0, __builtin_bit_cast(int, v), CTRL, 0xF, 0xF, true));
}

template<int CTRL>
__device__ __forceinline__ void stage_dpp(float4& v1, float4& v2, float sgn) {
    float o;
    o = xchg_dpp<CTRL>(v1.x); v1.x = fmaf(sgn, v1.x, o);
    o = xchg_dpp<CTRL>(v1.y); v1.y = fmaf(sgn, v1.y, o);
    o = xchg_dpp<CTRL>(v1.z); v1.z = fmaf(sgn, v1.z, o);
    o = xchg_dpp<CTRL>(v1.w); v1.w = fmaf(sgn, v1.w, o);
    o = xchg_dpp<CTRL>(v2.x); v2.x = fmaf(sgn, v2.x, o);
    o = xchg_dpp<CTRL>(v2.y); v2.y = fmaf(sgn, v2.y, o);
    o = xchg_dpp<CTRL>(v2.z); v2.z = fmaf(sgn, v2.z, o);
    o = xchg_dpp<CTRL>(v2.w); v2.w = fmaf(sgn, v2.w, o);
}

__device__ __forceinline__ void stage_shfl(float4& v1, float4& v2, float sgn, int mask) {
    float o;
    o = __shfl_xor(v1.x, mask, 64); v1.x = fmaf(sgn, v1.x, o);
    o = __shfl_xor(v1.y, mask, 64); v1.y = fmaf(sgn, v1.y, o);
    o = __shfl_xor(v1.z, mask, 64); v1.z = fmaf(sgn, v1.z, o);
    o = __shfl_xor(v1.w, mask, 64); v1.w = fmaf(sgn, v1.w, o);
    o = __shfl_xor(v2.x, mask, 64); v2.x = fmaf(sgn, v2.x, o);
    o = __shfl_xor(v2.y, mask, 64); v2.y = fmaf(sgn, v2.y, o);
    o = __shfl_xor(v2.z, mask, 64); v2.z = fmaf(sgn, v2.z, o);
    o = __shfl_xor(v2.w, mask, 64); v2.w = fmaf(sgn, v2.w, o);
}

// One block per batch row: 8 phases x 32 chunks through a 32.9 KB LDS tile.
// Per phase: dual-chunk wave FWHT -> freq-ordered LDS scatter -> transposed
// coalesced coeffs write. Entropy A/B partials live in registers across all
// phases; the block finalizes entropy/keep (and the rare !keep zeroing) itself.
// No workspace, no second kernel, no cross-block synchronization.
__global__ __launch_bounds__(NTHR) void wht_row(const float* __restrict__ x,
                                                float* __restrict__ coeffs,
                                                float* __restrict__ entropy,
                                                float* __restrict__ keep) {
    __shared__ float lds[KG][LSTR]; // 32.9 KB; reused as 8x2x256 partial buffer later

    const int b    = blockIdx.x;       // batch row
    const int lane = threadIdx.x & 63;
    const int wave = threadIdx.x >> 6; // 0..7
    const int half = lane >> 5;        // which of 2 concurrent chunks
    const int L    = lane & 31;        // position within chunk (j-bits 2..6)

    const float* xb = x + (size_t)b * T;

    // lane owns the SAME 8 nodes (h = 4L+i and 128+4L+i) in every chunk
    int npos1[4], npos2[4];
    #pragma unroll
    for (int i = 0; i < 4; ++i) {
        npos1[i] = freq_pos(4 * L + i);
        npos2[i] = freq_pos(128 + 4 * L + i);
    }
    float A1[4] = {0.f,0.f,0.f,0.f}, B1[4] = {0.f,0.f,0.f,0.f};
    float A2[4] = {0.f,0.f,0.f,0.f}, B2[4] = {0.f,0.f,0.f,0.f};

    // Butterfly signs for the 5 cross-lane stages (loop-invariant)
    const float sgn0 = 1.0f - 2.0f * (float)((L >> 0) & 1);
    const float sgn1 = 1.0f - 2.0f * (float)((L >> 1) & 1);
    const float sgn2 = 1.0f - 2.0f * (float)((L >> 2) & 1);
    const float sgn3 = 1.0f - 2.0f * (float)((L >> 3) & 1);
    const float sgn4 = 1.0f - 2.0f * (float)((L >> 4) & 1);

    // Each wave owns 4 chunks per phase (2 iterations x 2 lane-halves)
    const int kl0 = wave * 4 + half;     // it = 0
    const int kl1 = wave * 4 + 2 + half; // it = 1
    const int col = 4 * L;

    // Preload phase 0 into registers (prefetch depth 1 across phases)
    float4 c0a = *(const float4*)(xb + (size_t)kl0 * CL + col);
    float4 c0b = *(const float4*)(xb + (size_t)kl0 * CL + col + 128);
    float4 c1a = *(const float4*)(xb + (size_t)kl1 * CL + col);
    float4 c1b = *(const float4*)(xb + (size_t)kl1 * CL + col + 128);

    #pragma unroll
    for (int ph = 0; ph < NPH; ++ph) {
        // Issue next phase's loads first — they retire under this phase's compute
        float4 n0a, n0b, n1a, n1b;
        if (ph + 1 < NPH) {
            const float* q0 = xb + (size_t)((ph + 1) * KG + kl0) * CL + col;
            const float* q1 = xb + (size_t)((ph + 1) * KG + kl1) * CL + col;
            n0a = *(const float4*)(q0);
            n0b = *(const float4*)(q0 + 128);
            n1a = *(const float4*)(q1);
            n1b = *(const float4*)(q1 + 128);
        }

        // ---- FWHT + scatter for the two chunks this thread handles ----
        #pragma unroll
        for (int it = 0; it < 2; ++it) {
            const int kl = (it == 0) ? kl0 : kl1;
            float4 v1 = (it == 0) ? c0a : c1a;
            float4 v2 = (it == 0) ? c0b : c1b;

            // FWHT stage j-bit7 (across the two registers, pure VALU)
            float4 t;
            t.x = v1.x - v2.x; t.y = v1.y - v2.y; t.z = v1.z - v2.z; t.w = v1.w - v2.w;
            v1.x += v2.x; v1.y += v2.y; v1.z += v2.z; v1.w += v2.w;
            v2 = t;

            bfly01(v1);
            bfly01(v2);

            // FWHT stages j-bits 2..6 = lane xor 1,2,4,8,16
            stage_dpp<0xB1>(v1, v2, sgn0);   // xor 1
            stage_dpp<0x4E>(v1, v2, sgn1);   // xor 2
            stage_shfl(v1, v2, sgn2, 4);     // xor 4
            stage_dpp<0x128>(v1, v2, sgn3);  // xor 8
            stage_shfl(v1, v2, sgn4, 16);    // xor 16

            // scale by (1/sqrt2)^8 = 1/16; entropy partials; freq-ordered scatter
            float c1r[4] = {v1.x*0.0625f, v1.y*0.0625f, v1.z*0.0625f, v1.w*0.0625f};
            float c2r[4] = {v2.x*0.0625f, v2.y*0.0625f, v2.z*0.0625f, v2.w*0.0625f};
            #pragma unroll
            for (int i = 0; i < 4; ++i) {
                const float s1 = c1r[i] * c1r[i];
                A1[i] += s1;
                B1[i] += s1 * __logf(s1 + 1e-35f); // c=0 -> term 0
                lds[kl][npos1[i]] = c1r[i];
                const float s2 = c2r[i] * c2r[i];
                A2[i] += s2;
                B2[i] += s2 * __logf(s2 + 1e-35f);
                lds[kl][npos2[i]] = c2r[i];
            }
        }
        __syncthreads();

        // ---- transposed, coalesced write: coeffs[b][m][ph*KG + kk .. kk+3] ----
        float* ob = coeffs + (size_t)b * T + ph * KG;
        const int kk = (threadIdx.x & 7) * 4; // k offset within phase (0..28)
        const int m0 = threadIdx.x >> 3;      // 0..63
        #pragma unroll
        for (int p = 0; p < 4; ++p) {
            const int m = p * 64 + m0;
            float4 v;
            v.x = lds[kk + 0][m];
            v.y = lds[kk + 1][m];
            v.z = lds[kk + 2][m];
            v.w = lds[kk + 3][m];
            *(float4*)(ob + (size_t)m * NCH + kk) = v;
        }
        __syncthreads(); // protect LDS reuse by next phase's scatter

        c0a = n0a; c0b = n0b; c1a = n1a; c1b = n1b;
    }

    // ---- entropy finalize, fully in-block ----
    // Merge the two lane-halves (same node sets)
    #pragma unroll
    for (int i = 0; i < 4; ++i) {
        A1[i] += __shfl_xor(A1[i], 32, 64); B1[i] += __shfl_xor(B1[i], 32, 64);
        A2[i] += __shfl_xor(A2[i], 32, 64); B2[i] += __shfl_xor(B2[i], 32, 64);
    }
    float* pl = &lds[0][0]; // need 8*512 = 4096 floats, have 32*257 = 8224
    if (half == 0) {
        #pragma unroll
        for (int i = 0; i < 4; ++i) {
            pl[wave * 512 + npos1[i]]       = A1[i];
            pl[wave * 512 + 256 + npos1[i]] = B1[i];
            pl[wave * 512 + npos2[i]]       = A2[i];
            pl[wave * 512 + 256 + npos2[i]] = B2[i];
        }
    }
    __syncthreads();

    // Sum the 8 wave-partials; columns are thread-private (no extra barrier)
    const int idx = threadIdx.x; // 0..511
    float s = 0.f;
    #pragma unroll
    for (int w = 0; w < 8; ++w) s += pl[w * 512 + idx];
    pl[idx] = s;
    __syncthreads();

    if (idx < NODES) {
        const float A = pl[idx];
        const float B = pl[256 + idx];
        const float S = A + 1e-8f;
        const float e = (A * __logf(S) - B) / S;
        const bool kp = e > 0.1f;

        entropy[b * NODES + idx] = e;
        keep[b * NODES + idx]    = kp ? 1.0f : 0.0f;

        // Rare path (never fires for Gaussian input): zero this node's coeff row.
        // __syncthreads above drained this block's coeff stores -> same-CU ordering ok.
        if (!kp) {
            float4 z = make_float4(0.f, 0.f, 0.f, 0.f);
            float4* cp = (float4*)(coeffs + ((size_t)b * NODES + idx) * NCH);
            for (int j = 0; j < NCH / 4; ++j) cp[j] = z;
        }
    }
}

extern "C" void kernel_launch(void* const* d_in, const int* in_sizes, int n_in,
                              void* d_out, int out_size, void* d_ws, size_t ws_size,
                              hipStream_t stream) {
    const float* x = (const float*)d_in[0];

    float* coeffs  = (float*)d_out;                         // [128][256][256]
    float* entropy = coeffs + (size_t)BROWS * NODES * NCH;  // [128][256]
    float* keepf   = entropy + (size_t)BROWS * NODES;       // [128][256] as 0/1 float

    (void)d_ws; (void)ws_size; // no workspace needed — single fused kernel

    wht_row<<<dim3(BROWS), dim3(NTHR), 0, stream>>>(x, coeffs, entropy, keepf);
}